// Round 1
// baseline (435.167 us; speedup 1.0000x reference)
//
#include <hip/hip_runtime.h>
#include <math.h>

#define HWP 4096
#define CCH 256
#define NN  1024
#define DD  256
#define ZQ_SIZE (8 * DD * HWP)       // 8388608 floats
#define MARGIN 4e-3f                 // fp16 1-product screening: max gap-err ~6e-4, 7x safety
#define WLCAP 4096

typedef _Float16 h8 __attribute__((ext_vector_type(8)));
typedef float    f4 __attribute__((ext_vector_type(4)));

// ---------- K1: split w -> SWIZZLED fragment order, single fp16 copy ----------
// wS: [r16 0..63][kc 0..7][lane 0..63][j 0..7] halfs.
__global__ __launch_bounds__(256) void split_w_k(
    const float* __restrict__ w, _Float16* __restrict__ wS,
    int* __restrict__ wcount)
{
    if (blockIdx.x == 0 && threadIdx.x == 0) *wcount = 0;
    const int t = blockIdx.x * 256 + threadIdx.x;
    const int l = t & 63;
    const int frag = t >> 6;
    const int kc = frag & 7, r16 = frag >> 3;
    const int row = r16 * 16 + (l & 15);
    const int c   = kc * 32 + (l >> 4) * 8;
    const float* src = w + (size_t)row * CCH + c;
    _Float16 hv[8];
#pragma unroll
    for (int j = 0; j < 8; ++j) hv[j] = (_Float16)src[j];
    *(h8*)(wS + (size_t)t * 8) = *(const h8*)hv;
}

// ---------- K2: fused z-split + 1-product fp16 MFMA GEMM + top2 + gather ----------
// 512 blocks x 256 thr (4 waves). Block: 64 px x all 1024 n.
// LDS: zh [0,32K) | merge [32K,35K).  ~36 KB total -> 4 blocks/CU (16 waves/CU),
// double the latency hiding of the 3-product version (69 KB, 2 blocks/CU).
// K-loop: A via ds_read_b128 (lgkm), B via lane-contiguous dwordx4 from L2
// (vmcnt) — independent counters, no barriers. Single product; accuracy is
// handled by MARGIN + exact-fp32 fixup (error analysis: gap-err max ~6e-4).
__global__ __launch_bounds__(256, 4) void mfma_gemm_k(
    const float* __restrict__ z,
    const _Float16* __restrict__ wS,
    const float* __restrict__ bias, const float* __restrict__ embed,
    int* __restrict__ wcount, int* __restrict__ wlist,
    float* __restrict__ out)
{
    __shared__ __align__(16) char smem[35840];
    __shared__ int indsh2[64];
    float* s_best = (float*)(smem + 32768);     // [4][64]
    float* s_sec  = (float*)(smem + 33792);
    int*   s_idx  = (int*)  (smem + 34816);

    const int tid = threadIdx.x;
    const int l   = tid & 63;
    const int wv  = tid >> 6;
    const int c15 = l & 15, g = l >> 4;
    const int pix0 = blockIdx.x * 64;
    const int b = pix0 >> 12, p0 = pix0 & 4095;

    // ---- Stage A: z -> fp16 frag-order LDS ----
    // Frag (p16,kc) base = (p16*8+kc)*1024 B; lane entry +lane*16 B.
    {
        const int px = tid & 63;
        const int p16 = px >> 4;
        const float* zb = z + (size_t)b * CCH * HWP + p0 + px;
#pragma unroll
        for (int it = 0; it < 8; ++it) {
            const int cg = wv * 8 + it;          // c-group of 8 (0..31)
            const int c = cg * 8;
            float xv[8];
#pragma unroll
            for (int i = 0; i < 8; ++i) xv[i] = zb[(size_t)(c + i) * HWP];
            _Float16 hv[8];
#pragma unroll
            for (int i = 0; i < 8; ++i) hv[i] = (_Float16)xv[i];
            const int kc = cg >> 2;
            const int lane = (px & 15) + 16 * (cg & 3);
            const int off = ((p16 * 8 + kc) * 64 + lane) * 16;   // bytes, < 32768
            *(h8*)(smem + off) = *(const h8*)hv;
        }
    }
    __syncthreads();

    float best[16], sec[16]; int bidx[16];
#pragma unroll
    for (int s = 0; s < 16; ++s) { best[s] = -INFINITY; sec[s] = -INFINITY; bidx[s] = 0; }

#pragma unroll 1
    for (int nt = 0; nt < 4; ++nt) {
        const int n0 = nt * 256 + wv * 64;
        const int r16_0 = n0 >> 4;
        f4 acc[4][4];
#pragma unroll
        for (int mf = 0; mf < 4; ++mf)
#pragma unroll
            for (int nf = 0; nf < 4; ++nf) acc[mf][nf] = (f4)0.f;

#pragma unroll 2
        for (int kc = 0; kc < 8; ++kc) {
            h8 ah[4], bh[4];
#pragma unroll
            for (int mf = 0; mf < 4; ++mf) {
                const int ao = ((mf * 8 + kc) * 64 + l) * 16;
                ah[mf] = *(const h8*)(smem + ao);
            }
#pragma unroll
            for (int nf = 0; nf < 4; ++nf) {
                const size_t bo = (((size_t)(r16_0 + nf) * 8 + kc) * 64 + l) * 8;
                bh[nf] = *(const h8*)(wS + bo);
            }
#pragma unroll
            for (int mf = 0; mf < 4; ++mf)
#pragma unroll
                for (int nf = 0; nf < 4; ++nf)
                    acc[mf][nf] = __builtin_amdgcn_mfma_f32_16x16x32_f16(ah[mf], bh[nf], acc[mf][nf], 0, 0, 0);
        }
        // fold (+bias) into per-lane top2 (each lane's n ascend -> strict >)
#pragma unroll
        for (int nf = 0; nf < 4; ++nf) {
            const int n_abs = n0 + nf * 16 + c15;
            const float bv = bias[n_abs];
#pragma unroll
            for (int mf = 0; mf < 4; ++mf)
#pragma unroll
                for (int r = 0; r < 4; ++r) {
                    const float v = acc[mf][nf][r] + bv;
                    const int s = mf * 4 + r;
                    if (v > best[s]) { sec[s] = best[s]; best[s] = v; bidx[s] = n_abs; }
                    else if (v > sec[s]) sec[s] = v;
                }
        }
    }

    // butterfly over the 16 col-lanes (validated)
#pragma unroll
    for (int d = 1; d < 16; d <<= 1) {
#pragma unroll
        for (int s = 0; s < 16; ++s) {
            const float ob = __shfl_xor(best[s], d, 64);
            const float os = __shfl_xor(sec[s], d, 64);
            const int   oi = __shfl_xor(bidx[s], d, 64);
            if (ob > best[s])       { sec[s] = fmaxf(best[s], os); best[s] = ob; bidx[s] = oi; }
            else if (ob == best[s]) { sec[s] = ob; bidx[s] = (oi < bidx[s]) ? oi : bidx[s]; }
            else                    { sec[s] = fmaxf(sec[s], ob); }
        }
    }
    // publish: slot s -> pixel (s>>2)*16 + g*4 + (s&3)
#pragma unroll
    for (int s = 0; s < 16; ++s) {
        if (c15 == s) {
            const int px = (s >> 2) * 16 + g * 4 + (s & 3);
            s_best[wv * 64 + px] = best[s];
            s_sec [wv * 64 + px] = sec[s];
            s_idx [wv * 64 + px] = bidx[s];
        }
    }
    __syncthreads();
    if (tid < 64) {
        float b0 = s_best[tid], s0 = s_sec[tid]; int i0 = s_idx[tid];
#pragma unroll
        for (int c = 1; c < 4; ++c) {
            const float ob = s_best[c * 64 + tid], os = s_sec[c * 64 + tid];
            const int   oi = s_idx[c * 64 + tid];
            if (ob > b0 || (ob == b0 && oi < i0)) { s0 = fmaxf(b0, os); b0 = ob; i0 = oi; }
            else                                  { s0 = fmaxf(s0, ob); }
        }
        const int pix = pix0 + tid;
        indsh2[tid] = i0;
        out[ZQ_SIZE + 1 + pix] = (float)i0;
        if (b0 - s0 < MARGIN) {
            const int pos = atomicAdd(wcount, 1);
            if (pos < WLCAP) wlist[pos] = pix;
        }
    }
    if (blockIdx.x == 0 && tid == 0) out[ZQ_SIZE] = 0.0f;
    __syncthreads();   // merge consumed; staging LDS dead -> reuse as tile

    // ---- Gather epilogue: 2 passes of 32 px through a [32][257] LDS tile ----
    float (*tile)[257] = (float (*)[257])smem;   // 32896 B; overlaps dead zh + s_best
    const int lq = tid & 63, wq = tid >> 6;
    const int l32 = tid & 31, dq = tid >> 5;
#pragma unroll 1
    for (int pp = 0; pp < 2; ++pp) {
#pragma unroll
        for (int it = 0; it < 8; ++it) {
            const int pl = it * 4 + wq;          // 0..31
            const int row = indsh2[pp * 32 + pl];
            const float4 e = *(const float4*)(embed + (size_t)row * DD + lq * 4);
            tile[pl][lq * 4 + 0] = e.x;
            tile[pl][lq * 4 + 1] = e.y;
            tile[pl][lq * 4 + 2] = e.z;
            tile[pl][lq * 4 + 3] = e.w;
        }
        __syncthreads();
        float* outz = out + (size_t)b * DD * HWP + p0 + pp * 32;
#pragma unroll
        for (int dd = 0; dd < 32; ++dd) {
            const int d = dd * 8 + dq;
            outz[(size_t)d * HWP + l32] = tile[l32][d];
        }
        __syncthreads();
    }
}

// ---------- K3: exact-fp32 fixup (R8-validated core) + z_q rewrite ----------
// Grid raised 256 -> 2048: expected wcount ~1000 with fp16 screening, so each
// block handles <=1 pixel (was 256 blocks x serial pixels).
__global__ __launch_bounds__(256) void fixup_k(
    const float* __restrict__ z, const float* __restrict__ w,
    const float* __restrict__ bias, const float* __restrict__ embed,
    const int* __restrict__ wcount, const int* __restrict__ wlist,
    float* __restrict__ out)
{
    __shared__ float zsh[256];
    __shared__ float m_v[4];
    __shared__ int   m_i[4];
    __shared__ int   s_i;

    const int tid = threadIdx.x;
    const int l = tid & 63, wv = tid >> 6;
    const int c15 = l & 15, q = l >> 4;
    int nw = *wcount;
    if (nw > WLCAP) nw = WLCAP;

    for (int e = blockIdx.x; e < nw; e += 2048) {
        const int pix = wlist[e];
        const int b = pix >> 12, p = pix & 4095;
        __syncthreads();
        zsh[tid] = z[((size_t)b * CCH + tid) * HWP + p];
        __syncthreads();

        float best = -INFINITY; int bi = 0;
        for (int g16 = 0; g16 < 16; ++g16) {
            const int row = wv * 256 + g16 * 16 + c15;
            const float* wr = w + (size_t)row * CCH + q * 64;
            float part = 0.f;
#pragma unroll
            for (int j = 0; j < 16; ++j) {
                const float4 w4 = *(const float4*)(wr + j * 4);
                const float4 z4 = *(const float4*)&zsh[q * 64 + j * 4];
                part = fmaf(w4.x, z4.x, part);
                part = fmaf(w4.y, z4.y, part);
                part = fmaf(w4.z, z4.z, part);
                part = fmaf(w4.w, z4.w, part);
            }
            part += __shfl_xor(part, 16, 64);
            part += __shfl_xor(part, 32, 64);
            const float v = part + bias[row];
            if (v > best) { best = v; bi = row; }
        }
#pragma unroll
        for (int d = 1; d < 16; d <<= 1) {
            const float ob = __shfl_xor(best, d, 64);
            const int   oi = __shfl_xor(bi, d, 64);
            if (ob > best || (ob == best && oi < bi)) { best = ob; bi = oi; }
        }
        if (l == 0) { m_v[wv] = best; m_i[wv] = bi; }
        __syncthreads();
        if (tid == 0) {
            float v = m_v[0]; int i = m_i[0];
#pragma unroll
            for (int t = 1; t < 4; ++t)
                if (m_v[t] > v || (m_v[t] == v && m_i[t] < i)) { v = m_v[t]; i = m_i[t]; }
            s_i = i;
            out[ZQ_SIZE + 1 + pix] = (float)i;
        }
        __syncthreads();
        const int ii = s_i;
        out[((size_t)b * DD + tid) * HWP + p] = embed[(size_t)ii * DD + tid];
    }
}

extern "C" void kernel_launch(void* const* d_in, const int* in_sizes, int n_in,
                              void* d_out, int out_size, void* d_ws, size_t ws_size,
                              hipStream_t stream) {
    const float* z     = (const float*)d_in[0];
    const float* w     = (const float*)d_in[1];
    const float* bias  = (const float*)d_in[2];
    const float* embed = (const float*)d_in[3];
    float* out = (float*)d_out;

    // ws: wS 512K | wcount | wlist (16K)  — total ~541 KB (within proven 1.02 MB budget)
    _Float16* wS = (_Float16*)d_ws;
    int* wcount = (int*)((char*)d_ws + 524288);
    int* wlist  = (int*)((char*)d_ws + 524544);

    hipLaunchKernelGGL(split_w_k,   dim3(128), dim3(256), 0, stream, w, wS, wcount);
    hipLaunchKernelGGL(mfma_gemm_k, dim3(512), dim3(256), 0, stream,
                       z, wS, bias, embed, wcount, wlist, out);
    hipLaunchKernelGGL(fixup_k,     dim3(2048), dim3(256), 0, stream,
                       z, w, bias, embed, wcount, wlist, out);
}

// Round 2
// 180.921 us; speedup vs baseline: 2.4053x; 2.4053x over previous
//
#include <hip/hip_runtime.h>
#include <math.h>

#define HWP 4096
#define CCH 256
#define NN  1024
#define DD  256
#define ZQ_SIZE (8 * DD * HWP)       // 8388608 floats
#define MARGIN 1e-4f                 // 3-product hi/lo screening (R0-validated)
#define WLCAP 4096

typedef _Float16 h8 __attribute__((ext_vector_type(8)));
typedef float    f4 __attribute__((ext_vector_type(4)));

// ---------- K1: split w -> SWIZZLED fragment order (R0-validated) ----------
// whS/wlS: [r16 0..63][kc 0..7][lane 0..63][j 0..7] halfs.
__global__ __launch_bounds__(256) void split_w_k(
    const float* __restrict__ w, _Float16* __restrict__ whS, _Float16* __restrict__ wlS,
    int* __restrict__ wcount)
{
    if (blockIdx.x == 0 && threadIdx.x == 0) *wcount = 0;
    const int t = blockIdx.x * 256 + threadIdx.x;
    const int l = t & 63;
    const int frag = t >> 6;
    const int kc = frag & 7, r16 = frag >> 3;
    const int row = r16 * 16 + (l & 15);
    const int c   = kc * 32 + (l >> 4) * 8;
    const float* src = w + (size_t)row * CCH + c;
    _Float16 hv[8], lv[8];
#pragma unroll
    for (int j = 0; j < 8; ++j) {
        const float x = src[j];
        const _Float16 h = (_Float16)x;
        hv[j] = h;
        lv[j] = (_Float16)(x - (float)h);
    }
    *(h8*)(whS + (size_t)t * 8) = *(const h8*)hv;
    *(h8*)(wlS + (size_t)t * 8) = *(const h8*)lv;
}

// ---------- K2: fused z-split + 3-product MFMA GEMM + top2 + gather ----------
// CHANGE vs R0: 512 threads (8 waves) per block, same 64 px / 1024 n tile.
// Waves split (pixel-half mh = wv>>2) x (n-group ng = wv&3). Grid 512 =
// 2 blocks/CU but now 16 waves/CU (4/EU) — doubles latency hiding; B L2
// traffic unchanged (512 MB). Per-wave K-loop keeps the validated 3-product
// shape: 24 MFMA per kc vs 8 B-loads.
// LDS: zh [0,32K) | zl [32K,64K) | merge [64K,70K).
__global__ __launch_bounds__(512, 4) void mfma_gemm_k(
    const float* __restrict__ z,
    const _Float16* __restrict__ whS, const _Float16* __restrict__ wlS,
    const float* __restrict__ bias, const float* __restrict__ embed,
    int* __restrict__ wcount, int* __restrict__ wlist,
    float* __restrict__ out)
{
    __shared__ __align__(16) char smem[71680];
    __shared__ int indsh2[64];
    float* s_best = (float*)(smem + 65536);     // [8][64]
    float* s_sec  = (float*)(smem + 67584);
    int*   s_idx  = (int*)  (smem + 69632);

    const int tid = threadIdx.x;
    const int l   = tid & 63;
    const int wv  = tid >> 6;                   // 0..7
    const int mh  = wv >> 2;                    // pixel half: px in [32*mh, 32*mh+32)
    const int ng  = wv & 3;                     // n-group
    const int c15 = l & 15, g = l >> 4;
    const int pix0 = blockIdx.x * 64;
    const int b = pix0 >> 12, p0 = pix0 & 4095;

    // ---- Stage A: z -> hi/lo fp16 frag-order LDS ----
    // Frag (p16,kc) base = (p16*8+kc)*1024 B; lane entry +lane*16 B.
    {
        const int px = tid & 63;
        const int wv2 = tid >> 6;                // 0..7
        const int p16 = px >> 4;
        const float* zb = z + (size_t)b * CCH * HWP + p0 + px;
#pragma unroll
        for (int it = 0; it < 4; ++it) {
            const int cg = wv2 * 4 + it;         // c-group of 8 (0..31)
            const int c = cg * 8;
            float xv[8];
#pragma unroll
            for (int i = 0; i < 8; ++i) xv[i] = zb[(size_t)(c + i) * HWP];
            _Float16 hv[8], lv[8];
#pragma unroll
            for (int i = 0; i < 8; ++i) {
                const _Float16 h = (_Float16)xv[i];
                hv[i] = h;
                lv[i] = (_Float16)(xv[i] - (float)h);
            }
            const int kc = cg >> 2;
            const int lane = (px & 15) + 16 * (cg & 3);
            const int off = ((p16 * 8 + kc) * 64 + lane) * 16;   // bytes, < 32768
            *(h8*)(smem + off)         = *(const h8*)hv;
            *(h8*)(smem + 32768 + off) = *(const h8*)lv;
        }
    }
    __syncthreads();

    float best[8], sec[8]; int bidx[8];
#pragma unroll
    for (int s = 0; s < 8; ++s) { best[s] = -INFINITY; sec[s] = -INFINITY; bidx[s] = 0; }

#pragma unroll 1
    for (int nt = 0; nt < 4; ++nt) {
        const int n0 = nt * 256 + ng * 64;
        const int r16_0 = n0 >> 4;
        f4 acc[2][4];
#pragma unroll
        for (int mf = 0; mf < 2; ++mf)
#pragma unroll
            for (int nf = 0; nf < 4; ++nf) acc[mf][nf] = (f4)0.f;

#pragma unroll 2
        for (int kc = 0; kc < 8; ++kc) {
            h8 ah[2], al[2], bh[4], bl[4];
#pragma unroll
            for (int mf = 0; mf < 2; ++mf) {
                const int ao = (((mh * 2 + mf) * 8 + kc) * 64 + l) * 16;
                ah[mf] = *(const h8*)(smem + ao);
                al[mf] = *(const h8*)(smem + 32768 + ao);
            }
#pragma unroll
            for (int nf = 0; nf < 4; ++nf) {
                const size_t bo = (((size_t)(r16_0 + nf) * 8 + kc) * 64 + l) * 8;
                bh[nf] = *(const h8*)(whS + bo);
                bl[nf] = *(const h8*)(wlS + bo);
            }
#pragma unroll
            for (int mf = 0; mf < 2; ++mf)
#pragma unroll
                for (int nf = 0; nf < 4; ++nf) {
                    acc[mf][nf] = __builtin_amdgcn_mfma_f32_16x16x32_f16(ah[mf], bh[nf], acc[mf][nf], 0, 0, 0);
                    acc[mf][nf] = __builtin_amdgcn_mfma_f32_16x16x32_f16(ah[mf], bl[nf], acc[mf][nf], 0, 0, 0);
                    acc[mf][nf] = __builtin_amdgcn_mfma_f32_16x16x32_f16(al[mf], bh[nf], acc[mf][nf], 0, 0, 0);
                }
        }
        // fold (+bias) into per-lane top2 (each lane's n ascend -> strict >)
#pragma unroll
        for (int nf = 0; nf < 4; ++nf) {
            const int n_abs = n0 + nf * 16 + c15;
            const float bv = bias[n_abs];
#pragma unroll
            for (int mf = 0; mf < 2; ++mf)
#pragma unroll
                for (int r = 0; r < 4; ++r) {
                    const float v = acc[mf][nf][r] + bv;
                    const int s = mf * 4 + r;
                    if (v > best[s]) { sec[s] = best[s]; best[s] = v; bidx[s] = n_abs; }
                    else if (v > sec[s]) sec[s] = v;
                }
        }
    }

    // butterfly over the 16 col-lanes (validated)
#pragma unroll
    for (int d = 1; d < 16; d <<= 1) {
#pragma unroll
        for (int s = 0; s < 8; ++s) {
            const float ob = __shfl_xor(best[s], d, 64);
            const float os = __shfl_xor(sec[s], d, 64);
            const int   oi = __shfl_xor(bidx[s], d, 64);
            if (ob > best[s])       { sec[s] = fmaxf(best[s], os); best[s] = ob; bidx[s] = oi; }
            else if (ob == best[s]) { sec[s] = ob; bidx[s] = (oi < bidx[s]) ? oi : bidx[s]; }
            else                    { sec[s] = fmaxf(sec[s], ob); }
        }
    }
    // publish: wave wv, slot s, lane-group g -> pixel (2*mh + (s>>2))*16 + g*4 + (s&3)
#pragma unroll
    for (int s = 0; s < 8; ++s) {
        if (c15 == s) {
            const int px = (mh * 2 + (s >> 2)) * 16 + g * 4 + (s & 3);
            s_best[wv * 64 + px] = best[s];
            s_sec [wv * 64 + px] = sec[s];
            s_idx [wv * 64 + px] = bidx[s];
        }
    }
    __syncthreads();
    if (tid < 64) {
        // combine the 4 n-group waves of this pixel's half
        const int wb = (tid >> 5) * 4;
        float b0 = s_best[wb * 64 + tid], s0 = s_sec[wb * 64 + tid]; int i0 = s_idx[wb * 64 + tid];
#pragma unroll
        for (int c = 1; c < 4; ++c) {
            const float ob = s_best[(wb + c) * 64 + tid], os = s_sec[(wb + c) * 64 + tid];
            const int   oi = s_idx [(wb + c) * 64 + tid];
            if (ob > b0 || (ob == b0 && oi < i0)) { s0 = fmaxf(b0, os); b0 = ob; i0 = oi; }
            else                                  { s0 = fmaxf(s0, ob); }
        }
        const int pix = pix0 + tid;
        indsh2[tid] = i0;
        out[ZQ_SIZE + 1 + pix] = (float)i0;
        if (b0 - s0 < MARGIN) {
            const int pos = atomicAdd(wcount, 1);
            if (pos < WLCAP) wlist[pos] = pix;
        }
    }
    if (blockIdx.x == 0 && tid == 0) out[ZQ_SIZE] = 0.0f;
    __syncthreads();   // merge consumed; staging LDS dead -> reuse as tile

    // ---- Gather epilogue: 2 passes of 32 px through a [32][257] LDS tile ----
    float (*tile)[257] = (float (*)[257])smem;   // 32896 B, within dead staging LDS
    const int lq = tid & 63, wq = tid >> 6;      // wq 0..7
    const int l32 = tid & 31, dq = tid >> 5;     // dq 0..15
#pragma unroll 1
    for (int pp = 0; pp < 2; ++pp) {
#pragma unroll
        for (int it = 0; it < 4; ++it) {
            const int pl = it * 8 + wq;          // 0..31
            const int row = indsh2[pp * 32 + pl];
            const float4 e = *(const float4*)(embed + (size_t)row * DD + lq * 4);
            tile[pl][lq * 4 + 0] = e.x;
            tile[pl][lq * 4 + 1] = e.y;
            tile[pl][lq * 4 + 2] = e.z;
            tile[pl][lq * 4 + 3] = e.w;
        }
        __syncthreads();
        float* outz = out + (size_t)b * DD * HWP + p0 + pp * 32;
#pragma unroll
        for (int dd = 0; dd < 16; ++dd) {
            const int d = dd * 16 + dq;
            outz[(size_t)d * HWP + l32] = tile[l32][d];
        }
        __syncthreads();
    }
}

// ---------- K3: exact-fp32 fixup (R0-validated, wcount expected ~tens) ----------
__global__ __launch_bounds__(256) void fixup_k(
    const float* __restrict__ z, const float* __restrict__ w,
    const float* __restrict__ bias, const float* __restrict__ embed,
    const int* __restrict__ wcount, const int* __restrict__ wlist,
    float* __restrict__ out)
{
    __shared__ float zsh[256];
    __shared__ float m_v[4];
    __shared__ int   m_i[4];
    __shared__ int   s_i;

    const int tid = threadIdx.x;
    const int l = tid & 63, wv = tid >> 6;
    const int c15 = l & 15, q = l >> 4;
    int nw = *wcount;
    if (nw > WLCAP) nw = WLCAP;

    for (int e = blockIdx.x; e < nw; e += 256) {
        const int pix = wlist[e];
        const int b = pix >> 12, p = pix & 4095;
        __syncthreads();
        zsh[tid] = z[((size_t)b * CCH + tid) * HWP + p];
        __syncthreads();

        float best = -INFINITY; int bi = 0;
        for (int g16 = 0; g16 < 16; ++g16) {
            const int row = wv * 256 + g16 * 16 + c15;
            const float* wr = w + (size_t)row * CCH + q * 64;
            float part = 0.f;
#pragma unroll
            for (int j = 0; j < 16; ++j) {
                const float4 w4 = *(const float4*)(wr + j * 4);
                const float4 z4 = *(const float4*)&zsh[q * 64 + j * 4];
                part = fmaf(w4.x, z4.x, part);
                part = fmaf(w4.y, z4.y, part);
                part = fmaf(w4.z, z4.z, part);
                part = fmaf(w4.w, z4.w, part);
            }
            part += __shfl_xor(part, 16, 64);
            part += __shfl_xor(part, 32, 64);
            const float v = part + bias[row];
            if (v > best) { best = v; bi = row; }
        }
#pragma unroll
        for (int d = 1; d < 16; d <<= 1) {
            const float ob = __shfl_xor(best, d, 64);
            const int   oi = __shfl_xor(bi, d, 64);
            if (ob > best || (ob == best && oi < bi)) { best = ob; bi = oi; }
        }
        if (l == 0) { m_v[wv] = best; m_i[wv] = bi; }
        __syncthreads();
        if (tid == 0) {
            float v = m_v[0]; int i = m_i[0];
#pragma unroll
            for (int t = 1; t < 4; ++t)
                if (m_v[t] > v || (m_v[t] == v && m_i[t] < i)) { v = m_v[t]; i = m_i[t]; }
            s_i = i;
            out[ZQ_SIZE + 1 + pix] = (float)i;
        }
        __syncthreads();
        const int ii = s_i;
        out[((size_t)b * DD + tid) * HWP + p] = embed[(size_t)ii * DD + tid];
    }
}

extern "C" void kernel_launch(void* const* d_in, const int* in_sizes, int n_in,
                              void* d_out, int out_size, void* d_ws, size_t ws_size,
                              hipStream_t stream) {
    const float* z     = (const float*)d_in[0];
    const float* w     = (const float*)d_in[1];
    const float* bias  = (const float*)d_in[2];
    const float* embed = (const float*)d_in[3];
    float* out = (float*)d_out;

    // ws (1.02 MB — proven budget): whS 512K | wlS 512K | wcount | wlist
    _Float16* whS = (_Float16*)d_ws;
    _Float16* wlS = (_Float16*)((char*)d_ws + 524288);
    int* wcount = (int*)((char*)d_ws + 1048576);
    int* wlist  = (int*)((char*)d_ws + 1048832);

    hipLaunchKernelGGL(split_w_k,   dim3(128), dim3(256), 0, stream, w, whS, wlS, wcount);
    hipLaunchKernelGGL(mfma_gemm_k, dim3(512), dim3(512), 0, stream,
                       z, whS, wlS, bias, embed, wcount, wlist, out);
    hipLaunchKernelGGL(fixup_k,     dim3(256), dim3(256), 0, stream,
                       z, w, bias, embed, wcount, wlist, out);
}